// Round 1
// baseline (824.553 us; speedup 1.0000x reference)
//
#include <hip/hip_runtime.h>

#define D_MODEL 2048
#define N_HEADS 32
#define D_HEAD  64
#define CHUNK   128
#define SEQ     2048
#define BZ      4
#define NC      16            // SEQ/CHUNK
#define NTOK    (BZ*SEQ)      // 8192
#define LN_EPS  1e-5f

typedef __bf16 bf16_t;
typedef bf16_t bf16x8 __attribute__((ext_vector_type(8)));
typedef float  f32x4  __attribute__((ext_vector_type(4)));

// ---------------------------------------------------------------------------
// K1: LayerNorm + token-shift time-mix -> rx,kx,vx (bf16). Also writes
// xn[:, -1, :] (output 1). One block per token; LN of the previous token is
// recomputed (cheap, L2-hot) instead of materializing xn.
// ---------------------------------------------------------------------------
__global__ __launch_bounds__(256) void k_ln_mix(
    const float* __restrict__ x, const float* __restrict__ tmr,
    const float* __restrict__ tmk, const float* __restrict__ tmv,
    const float* __restrict__ g1, const float* __restrict__ b1,
    bf16_t* __restrict__ rxb, bf16_t* __restrict__ kxb, bf16_t* __restrict__ vxb,
    float* __restrict__ xn_last)
{
    __shared__ float sbuf[16];
    const int row = blockIdx.x;
    const int t = row & (SEQ-1);
    const int tid = threadIdx.x;
    const float4* xc4 = (const float4*)(x + (size_t)row*D_MODEL);
    float4 c0 = xc4[tid*2], c1 = xc4[tid*2+1];
    float4 p0 = {0,0,0,0}, p1 = {0,0,0,0};
    const bool hasprev = (t != 0);
    if (hasprev){
        const float4* xp4 = (const float4*)(x + (size_t)(row-1)*D_MODEL);
        p0 = xp4[tid*2]; p1 = xp4[tid*2+1];
    }
    float xc[8] = {c0.x,c0.y,c0.z,c0.w,c1.x,c1.y,c1.z,c1.w};
    float xp[8] = {p0.x,p0.y,p0.z,p0.w,p1.x,p1.y,p1.z,p1.w};
    float sc=0.f, qc=0.f, sp=0.f, qp=0.f;
    for (int q=0;q<8;++q){ sc+=xc[q]; qc+=xc[q]*xc[q]; sp+=xp[q]; qp+=xp[q]*xp[q]; }
    for (int o=1;o<64;o<<=1){
        sc += __shfl_xor(sc,o,64); qc += __shfl_xor(qc,o,64);
        sp += __shfl_xor(sp,o,64); qp += __shfl_xor(qp,o,64);
    }
    const int wave = tid>>6, lane = tid&63;
    if (lane==0){ sbuf[wave*4+0]=sc; sbuf[wave*4+1]=qc; sbuf[wave*4+2]=sp; sbuf[wave*4+3]=qp; }
    __syncthreads();
    sc = sbuf[0]+sbuf[4]+sbuf[8]+sbuf[12];
    qc = sbuf[1]+sbuf[5]+sbuf[9]+sbuf[13];
    sp = sbuf[2]+sbuf[6]+sbuf[10]+sbuf[14];
    qp = sbuf[3]+sbuf[7]+sbuf[11]+sbuf[15];
    const float inv = 1.f/(float)D_MODEL;
    float muc = sc*inv, varc = qc*inv - muc*muc;
    float rc  = rsqrtf(varc + LN_EPS);
    float mup = sp*inv, varp = qp*inv - mup*mup;
    float rp  = rsqrtf(varp + LN_EPS);
    bf16x8 rv, kv, vv;
    const int ci = tid*8;
    float xnl[8];
    for (int q=0;q<8;++q){
        int c = ci+q;
        float gg = g1[c], bb = b1[c];
        float xn = (xc[q]-muc)*rc*gg + bb;
        float sh = hasprev ? ((xp[q]-mup)*rp*gg + bb) : 0.f;  // shift row 0 is literal 0
        float mr = tmr[c], mk = tmk[c], mv = tmv[c];
        rv[q] = (bf16_t)(xn*mr + (1.f-mr)*sh);
        kv[q] = (bf16_t)(xn*mk + (1.f-mk)*sh);
        vv[q] = (bf16_t)(xn*mv + (1.f-mv)*sh);
        xnl[q] = xn;
    }
    size_t base = (size_t)row*D_MODEL + ci;
    *(bf16x8*)&rxb[base] = rv;
    *(bf16x8*)&kxb[base] = kv;
    *(bf16x8*)&vxb[base] = vv;
    if (t == SEQ-1){
        int b = row >> 11;
        for (int q=0;q<8;++q) xn_last[(size_t)b*D_MODEL + ci + q] = xnl[q];
    }
}

// ---------------------------------------------------------------------------
// K2: transpose + f32->bf16 convert one weight matrix: WT[n][k] = W[k][n].
// Makes every GEMM a B^T gemm with contiguous K-fragments.
// ---------------------------------------------------------------------------
__global__ __launch_bounds__(256) void k_wt(const float* __restrict__ W, bf16_t* __restrict__ WT)
{
    __shared__ float tile[64][65];
    const int n0 = blockIdx.x*64, k0 = blockIdx.y*64;
    const int j = threadIdx.x & 63, i0 = threadIdx.x >> 6;
    for (int it=0; it<16; ++it){
        int i = i0 + it*4;
        tile[j][i] = W[(size_t)(k0+i)*D_MODEL + n0 + j];
    }
    __syncthreads();
    for (int it=0; it<16; ++it){
        int idx = threadIdx.x + it*256;
        int r = idx >> 6, c = idx & 63;
        WT[(size_t)(n0+r)*D_MODEL + k0 + c] = (bf16_t)tile[r][c];
    }
}

// ---------------------------------------------------------------------------
// K3: bf16 GEMM, C = A(MxK) * B^T(NxK)^T. 128x128 tile, 4 waves of 64x64,
// mfma_f32_16x16x32_bf16, LDS padded +8 bf16 (2-way bank aliasing = free).
// OUT_BF16=1: store bf16. OUT_BF16=0: f32 out with fused residual add.
// ---------------------------------------------------------------------------
template<int OUT_BF16>
__global__ __launch_bounds__(256) void k_gemm_bt(
    const bf16_t* __restrict__ A, const bf16_t* __restrict__ B,
    void* __restrict__ Cout, const float* __restrict__ resid, int N, int K)
{
    __shared__ __align__(16) bf16_t As[128*40];
    __shared__ __align__(16) bf16_t Bs[128*40];
    const int tid = threadIdx.x;
    const int wave = tid>>6, lane = tid&63;
    const int quad = lane>>4, l15 = lane&15;
    const int wm = (wave>>1)*64, wn = (wave&1)*64;
    const size_t arow0 = (size_t)blockIdx.y*128;
    const size_t brow0 = (size_t)blockIdx.x*128;
    const int r0 = tid>>2, kc = (tid&3)*8;
    f32x4 acc[4][4];
    for (int i=0;i<4;++i) for (int j=0;j<4;++j) acc[i][j] = (f32x4){0.f,0.f,0.f,0.f};
    for (int k0=0; k0<K; k0+=32){
        for (int it=0; it<2; ++it){
            int row = r0 + it*64;
            *(bf16x8*)&As[row*40+kc] = *(const bf16x8*)&A[(arow0+row)*K + k0 + kc];
            *(bf16x8*)&Bs[row*40+kc] = *(const bf16x8*)&B[(brow0+row)*K + k0 + kc];
        }
        __syncthreads();
        bf16x8 af[4], bfr[4];
        for (int i=0;i<4;++i){
            af[i]  = *(const bf16x8*)&As[(wm+i*16+l15)*40 + quad*8];
            bfr[i] = *(const bf16x8*)&Bs[(wn+i*16+l15)*40 + quad*8];
        }
        for (int i=0;i<4;++i)
            for (int j=0;j<4;++j)
                acc[i][j] = __builtin_amdgcn_mfma_f32_16x16x32_bf16(af[i], bfr[j], acc[i][j], 0,0,0);
        __syncthreads();
    }
    for (int i=0;i<4;++i) for (int j=0;j<4;++j){
        for (int e=0;e<4;++e){
            size_t r = arow0 + wm + i*16 + quad*4 + e;
            size_t c = brow0 + wn + j*16 + l15;
            float v = acc[i][j][e];
            if (OUT_BF16) ((bf16_t*)Cout)[r*(size_t)N + c] = (bf16_t)v;
            else          ((float*) Cout)[r*(size_t)N + c] = resid[r*(size_t)N + c] + v;
        }
    }
}

// ---------------------------------------------------------------------------
// K4a: per (b,chunk,h): S = (r k^T) * w_mask (bf16 round-trip through LDS),
// sep = S v (f32 out). LDS overlay: SS reuses rS+kS after a barrier -> 53 KB.
// ---------------------------------------------------------------------------
__global__ __launch_bounds__(256) void k_chunk_att(
    const bf16_t* __restrict__ rb, const bf16_t* __restrict__ kb, const bf16_t* __restrict__ vb,
    const float* __restrict__ td, const float* __restrict__ tf, float* __restrict__ sep)
{
    __shared__ __align__(16) char smem[54272];
    bf16_t* rS = (bf16_t*)smem;               // [128][72]
    bf16_t* kS = (bf16_t*)(smem + 18432);     // [128][72]
    bf16_t* SS = (bf16_t*)smem;               // [128][136] overlays rS+kS
    bf16_t* vT = (bf16_t*)(smem + 36864);     // [64][136], vT[d][j] = v[j][d]
    const int bid = blockIdx.x;
    const int h = bid & 31, n = (bid>>5)&15, b = bid>>9;
    const int tid = threadIdx.x;
    const int wave = tid>>6, lane = tid&63, quad = lane>>4, l15 = lane&15;
    const size_t row0 = (size_t)b*SEQ + n*CHUNK;
    const int col0 = h*D_HEAD;
    const float lnw = -__expf(td[h]);
    const float u   =  __expf(tf[h]);
    for (int it=0; it<4; ++it){
        int idx = tid + it*256;
        int row = idx>>3, c8 = (idx&7)*8;
        *(bf16x8*)&rS[row*72 + c8] = *(const bf16x8*)&rb[(row0+row)*D_MODEL + col0 + c8];
        *(bf16x8*)&kS[row*72 + c8] = *(const bf16x8*)&kb[(row0+row)*D_MODEL + col0 + c8];
        bf16x8 vv = *(const bf16x8*)&vb[(row0+row)*D_MODEL + col0 + c8];
        for (int q=0;q<8;++q) vT[(c8+q)*136 + row] = vv[q];
    }
    __syncthreads();
    f32x4 accS[2][8];
    for (int i=0;i<2;++i) for (int j=0;j<8;++j) accS[i][j] = (f32x4){0.f,0.f,0.f,0.f};
    for (int kk=0; kk<2; ++kk){
        bf16x8 af[2], bfr[8];
        for (int i=0;i<2;++i) af[i] = *(const bf16x8*)&rS[(wave*32+i*16+l15)*72 + kk*32 + quad*8];
        for (int j=0;j<8;++j) bfr[j] = *(const bf16x8*)&kS[(j*16+l15)*72 + kk*32 + quad*8];
        for (int i=0;i<2;++i) for (int j=0;j<8;++j)
            accS[i][j] = __builtin_amdgcn_mfma_f32_16x16x32_bf16(af[i], bfr[j], accS[i][j], 0,0,0);
    }
    __syncthreads();   // everyone done reading rS/kS before SS overlays them
    for (int i=0;i<2;++i) for (int j=0;j<8;++j) for (int e=0;e<4;++e){
        int si = wave*32 + i*16 + quad*4 + e;
        int sj = j*16 + l15;
        float m;
        if (si > sj)      m = __expf(lnw * (float)(si-sj-1));
        else if (si == sj) m = u;
        else               m = 0.f;
        SS[si*136 + sj] = (bf16_t)(accS[i][j][e] * m);
    }
    __syncthreads();
    f32x4 accP[2][4];
    for (int i=0;i<2;++i) for (int j=0;j<4;++j) accP[i][j] = (f32x4){0.f,0.f,0.f,0.f};
    for (int kk=0; kk<4; ++kk){
        bf16x8 af[2], bfr[4];
        for (int i=0;i<2;++i) af[i] = *(const bf16x8*)&SS[(wave*32+i*16+l15)*136 + kk*32 + quad*8];
        for (int j=0;j<4;++j) bfr[j] = *(const bf16x8*)&vT[(j*16+l15)*136 + kk*32 + quad*8];
        for (int i=0;i<2;++i) for (int j=0;j<4;++j)
            accP[i][j] = __builtin_amdgcn_mfma_f32_16x16x32_bf16(af[i], bfr[j], accP[i][j], 0,0,0);
    }
    float* sepb = sep + (size_t)bid*(CHUNK*D_HEAD);
    for (int i=0;i<2;++i) for (int j=0;j<4;++j) for (int e=0;e<4;++e){
        int si = wave*32 + i*16 + quad*4 + e;
        int d  = j*16 + l15;
        sepb[si*D_HEAD + d] = accP[i][j][e];
    }
}

// ---------------------------------------------------------------------------
// K4b: per (b,chunk,h): U[e][d] = sum_j k[j][e] * w^(C-1-j) * v[j][d]
// (the chunk's contribution to the state recurrence).
// ---------------------------------------------------------------------------
__global__ __launch_bounds__(256) void k_chunk_U(
    const bf16_t* __restrict__ kb, const bf16_t* __restrict__ vb,
    const float* __restrict__ td, float* __restrict__ U)
{
    __shared__ __align__(16) bf16_t kT[64*136];   // kT[e][j] = k[j][e]*w^(127-j)
    __shared__ __align__(16) bf16_t vT[64*136];   // vT[d][j] = v[j][d]
    const int bid = blockIdx.x;
    const int h = bid & 31, n = (bid>>5)&15, b = bid>>9;
    const int tid = threadIdx.x;
    const int wave = tid>>6, lane = tid&63, quad = lane>>4, l15 = lane&15;
    const size_t row0 = (size_t)b*SEQ + n*CHUNK;
    const int col0 = h*D_HEAD;
    const float lnw = -__expf(td[h]);
    for (int it=0; it<4; ++it){
        int idx = tid + it*256;
        int row = idx>>3, c8 = (idx&7)*8;
        float wj = __expf(lnw * (float)(CHUNK-1-row));
        bf16x8 kv = *(const bf16x8*)&kb[(row0+row)*D_MODEL + col0 + c8];
        bf16x8 vv = *(const bf16x8*)&vb[(row0+row)*D_MODEL + col0 + c8];
        for (int q=0;q<8;++q){
            kT[(c8+q)*136 + row] = (bf16_t)((float)kv[q] * wj);
            vT[(c8+q)*136 + row] = vv[q];
        }
    }
    __syncthreads();
    f32x4 accU[4];
    for (int j=0;j<4;++j) accU[j] = (f32x4){0.f,0.f,0.f,0.f};
    for (int kk=0; kk<4; ++kk){
        bf16x8 af = *(const bf16x8*)&kT[(wave*16+l15)*136 + kk*32 + quad*8];
        bf16x8 bfr[4];
        for (int j=0;j<4;++j) bfr[j] = *(const bf16x8*)&vT[(j*16+l15)*136 + kk*32 + quad*8];
        for (int j=0;j<4;++j)
            accU[j] = __builtin_amdgcn_mfma_f32_16x16x32_bf16(af, bfr[j], accU[j], 0,0,0);
    }
    float* Ub = U + (size_t)bid*(D_HEAD*D_HEAD);
    for (int j=0;j<4;++j) for (int e=0;e<4;++e){
        int ei = wave*16 + quad*4 + e;
        int d  = j*16 + l15;
        Ub[ei*D_HEAD + d] = accU[j][e];
    }
}

// ---------------------------------------------------------------------------
// K5: sequential prefix over chunks (per b,h): emit per-chunk incoming state
// (bf16, transposed [d][e] for the bias MFMA B-operand) and final state (out 2).
// ---------------------------------------------------------------------------
__global__ __launch_bounds__(256) void k_scan(
    const float* __restrict__ U, const float* __restrict__ td,
    bf16_t* __restrict__ stT, float* __restrict__ outState)
{
    const int bh = blockIdx.x;
    const int h = bh & 31, b = bh >> 5;
    const int tid = threadIdx.x;
    const float lnw = -__expf(td[h]);
    const float wC  =  __expf(lnw * (float)CHUNK);
    float st[16];
    for (int q=0;q<16;++q) st[q] = 0.f;
    for (int n=0;n<NC;++n){
        size_t base = ((size_t)((b*NC + n)*N_HEADS + h))*4096;
        for (int q=0;q<16;++q){
            int f = tid + q*256;
            int e = f>>6, d = f&63;
            stT[base + d*64 + e] = (bf16_t)st[q];       // incoming state for chunk n
            st[q] = st[q]*wC + U[base + f];
        }
    }
    size_t ob = ((size_t)(b*N_HEADS + h))*4096;
    for (int q=0;q<16;++q) outState[ob + tid + q*256] = st[q];
}

// ---------------------------------------------------------------------------
// K6: per (b,chunk,h): bias = (r @ state)*w^i, att_pre = sep + bias,
// LayerNorm over d_head with lnx scale/bias, write att (bf16, token-major).
// ---------------------------------------------------------------------------
__global__ __launch_bounds__(256) void k_bias_ln(
    const bf16_t* __restrict__ rb, const bf16_t* __restrict__ stT,
    const float* __restrict__ sep, const float* __restrict__ td,
    const float* __restrict__ gx, const float* __restrict__ bx,
    bf16_t* __restrict__ att)
{
    __shared__ __align__(16) bf16_t rS[128*72];
    __shared__ __align__(16) bf16_t sS[64*72];
    __shared__ float ap[128*68];
    __shared__ float mu_s[128], rs_s[128];
    const int bid = blockIdx.x;
    const int h = bid & 31, n = (bid>>5)&15, b = bid>>9;
    const int tid = threadIdx.x;
    const int wave = tid>>6, lane = tid&63, quad = lane>>4, l15 = lane&15;
    const size_t row0 = (size_t)b*SEQ + n*CHUNK;
    const int col0 = h*D_HEAD;
    const float lnw = -__expf(td[h]);
    for (int it=0; it<4; ++it){
        int idx = tid + it*256;
        int row = idx>>3, c8 = (idx&7)*8;
        *(bf16x8*)&rS[row*72 + c8] = *(const bf16x8*)&rb[(row0+row)*D_MODEL + col0 + c8];
    }
    const bf16_t* stg = stT + (size_t)bid*4096;
    for (int it=0; it<2; ++it){
        int idx = tid + it*256;
        int row = idx>>3, c8 = (idx&7)*8;
        *(bf16x8*)&sS[row*72 + c8] = *(const bf16x8*)&stg[row*64 + c8];
    }
    __syncthreads();
    f32x4 acc[2][4];
    for (int i=0;i<2;++i) for (int j=0;j<4;++j) acc[i][j] = (f32x4){0.f,0.f,0.f,0.f};
    for (int kk=0; kk<2; ++kk){
        bf16x8 af[2], bfr[4];
        for (int i=0;i<2;++i) af[i] = *(const bf16x8*)&rS[(wave*32+i*16+l15)*72 + kk*32 + quad*8];
        for (int j=0;j<4;++j) bfr[j] = *(const bf16x8*)&sS[(j*16+l15)*72 + kk*32 + quad*8];
        for (int i=0;i<2;++i) for (int j=0;j<4;++j)
            acc[i][j] = __builtin_amdgcn_mfma_f32_16x16x32_bf16(af[i], bfr[j], acc[i][j], 0,0,0);
    }
    const float* sepb = sep + (size_t)bid*(CHUNK*D_HEAD);
    for (int i=0;i<2;++i) for (int j=0;j<4;++j) for (int e=0;e<4;++e){
        int si = wave*32 + i*16 + quad*4 + e;
        int d  = j*16 + l15;
        ap[si*68 + d] = acc[i][j][e]*__expf(lnw*(float)si) + sepb[si*D_HEAD + d];
    }
    __syncthreads();
    if (tid < 128){
        float s=0.f, q2=0.f;
        for (int d=0; d<64; ++d){ float v = ap[tid*68+d]; s += v; q2 += v*v; }
        float mu = s*(1.f/64.f);
        float var = q2*(1.f/64.f) - mu*mu;
        mu_s[tid] = mu; rs_s[tid] = rsqrtf(var + LN_EPS);
    }
    __syncthreads();
    for (int it=0; it<4; ++it){
        int idx = tid + it*256;
        int i = idx>>3, c8 = (idx&7)*8;
        float mu = mu_s[i], rs = rs_s[i];
        bf16x8 o;
        for (int q=0;q<8;++q){
            int d = c8+q;
            o[q] = (bf16_t)((ap[i*68+d]-mu)*rs*gx[col0+d] + bx[col0+d]);
        }
        *(bf16x8*)&att[(row0+i)*D_MODEL + col0 + c8] = o;
    }
}

// ---------------------------------------------------------------------------
// Launch. Workspace layout (requires ws_size >= 224 MiB), with aliasing:
//   [0,32)   rxb bf16        -> later sep f32 [0,64)
//   [32,64)  kxb bf16
//   [64,96)  vxb bf16        -> later U f32 [64,96) -> later att bf16 [64,96)
//   [96,104) WrT bf16        -> later stT bf16 [96,112)
//   [104,112) WkT, [112,120) WvT, [120,128) WoT (WoT alive to the end)
//   [128,160) rb, [160,192) kb, [192,224) vb   (bf16 GEMM outputs)
// ---------------------------------------------------------------------------
extern "C" void kernel_launch(void* const* d_in, const int* in_sizes, int n_in,
                              void* d_out, int out_size, void* d_ws, size_t ws_size,
                              hipStream_t stream) {
    const float* x   = (const float*)d_in[0];
    const float* tmr = (const float*)d_in[1];
    const float* tmk = (const float*)d_in[2];
    const float* tmv = (const float*)d_in[3];
    const float* Wk  = (const float*)d_in[4];
    const float* Wv  = (const float*)d_in[5];
    const float* Wr  = (const float*)d_in[6];
    const float* Wo  = (const float*)d_in[7];
    const float* td  = (const float*)d_in[8];
    const float* tf  = (const float*)d_in[9];
    const float* g1  = (const float*)d_in[10];
    const float* b1  = (const float*)d_in[11];
    const float* gx  = (const float*)d_in[12];
    const float* bx  = (const float*)d_in[13];

    float* out0 = (float*)d_out;                       // inputs + out
    float* out1 = out0 + (size_t)NTOK*D_MODEL;         // xn[:, -1, :]
    float* out2 = out1 + (size_t)BZ*D_MODEL;           // final state

    const size_t MB = 1ull<<20;
    char* ws = (char*)d_ws;
    bf16_t* rxb = (bf16_t*)(ws);
    bf16_t* kxb = (bf16_t*)(ws + 32*MB);
    bf16_t* vxb = (bf16_t*)(ws + 64*MB);
    bf16_t* WrT = (bf16_t*)(ws + 96*MB);
    bf16_t* WkT = (bf16_t*)(ws + 104*MB);
    bf16_t* WvT = (bf16_t*)(ws + 112*MB);
    bf16_t* WoT = (bf16_t*)(ws + 120*MB);
    bf16_t* rb  = (bf16_t*)(ws + 128*MB);
    bf16_t* kb  = (bf16_t*)(ws + 160*MB);
    bf16_t* vb  = (bf16_t*)(ws + 192*MB);
    float*  sep = (float*)(ws);                        // after rxb/kxb dead
    float*  U   = (float*)(ws + 64*MB);                // after vxb dead
    bf16_t* stT = (bf16_t*)(ws + 96*MB);               // after WrT/WkT dead
    bf16_t* att = (bf16_t*)(ws + 64*MB);               // after U dead

    k_ln_mix<<<NTOK, 256, 0, stream>>>(x, tmr, tmk, tmv, g1, b1, rxb, kxb, vxb, out1);

    dim3 gT(32, 32);
    k_wt<<<gT, 256, 0, stream>>>(Wr, WrT);
    k_wt<<<gT, 256, 0, stream>>>(Wk, WkT);
    k_wt<<<gT, 256, 0, stream>>>(Wv, WvT);
    k_wt<<<gT, 256, 0, stream>>>(Wo, WoT);

    dim3 gG(D_MODEL/128, NTOK/128);   // (16, 64)
    k_gemm_bt<1><<<gG, 256, 0, stream>>>(rxb, WrT, rb, nullptr, D_MODEL, D_MODEL);
    k_gemm_bt<1><<<gG, 256, 0, stream>>>(kxb, WkT, kb, nullptr, D_MODEL, D_MODEL);
    k_gemm_bt<1><<<gG, 256, 0, stream>>>(vxb, WvT, vb, nullptr, D_MODEL, D_MODEL);

    const int nblk = BZ*NC*N_HEADS;   // 2048
    k_chunk_att<<<nblk, 256, 0, stream>>>(rb, kb, vb, td, tf, sep);
    k_chunk_U  <<<nblk, 256, 0, stream>>>(kb, vb, td, U);
    k_scan     <<<BZ*N_HEADS, 256, 0, stream>>>(U, td, stT, out2);
    k_bias_ln  <<<nblk, 256, 0, stream>>>(rb, stT, sep, td, gx, bx, att);

    k_gemm_bt<0><<<gG, 256, 0, stream>>>(att, WoT, out0, x, D_MODEL, D_MODEL);
}